// Round 9
// baseline (191.667 us; speedup 1.0000x reference)
//
#include <hip/hip_runtime.h>

typedef _Float16 v8h __attribute__((ext_vector_type(8)));
typedef float v16f __attribute__((ext_vector_type(16)));

// BF frag counts (padded to 68 ko; ko64 = bias, ko>=65 zero)
#define NBF0 (68 * 2 * 2 * 512)   // layer0: PH=2
#define NBF1 (68 * 4 * 2 * 512)   // layer1: PH=4

// ---------------------------------------------------------------------------
// BF: B in MFMA-fragment order, padded to 68 ko (pad rows = 0).
// Fragment f = kk16*2 + nf holds at [lane*8 + j]:
//   B[k = kk16*16 + (lane>>5)*8 + j][o = nf*32 + (lane&31)]
// B[k][o] = ko<64 ? w2[ko, i*64+o] : (ko==64 ? b2[i*64+o] : 0), ko=k/IN.
// ---------------------------------------------------------------------------
__global__ void prep_bf_both(const float* __restrict__ w2_0, const float* __restrict__ b2_0,
                             _Float16* __restrict__ BF0,
                             const float* __restrict__ w2_1, const float* __restrict__ b2_1,
                             _Float16* __restrict__ BF1) {
    int idx = blockIdx.x * 256 + threadIdx.x;
    if (idx < NBF0) {
        int rel = idx;
        int j = rel & 7, lane = (rel >> 3) & 63, f = rel >> 9;
        int nf = f & 1, kk16 = f >> 1;
        int k = kk16 * 16 + (lane >> 5) * 8 + j;
        int ko = k >> 5, i = k & 31;
        int o = nf * 32 + (lane & 31);
        float v = (ko < 64) ? w2_0[ko * (32 * 64) + i * 64 + o]
                : (ko == 64 ? b2_0[i * 64 + o] : 0.f);
        BF0[rel] = (_Float16)v;
    } else if (idx < NBF0 + NBF1) {
        int rel = idx - NBF0;
        int j = rel & 7, lane = (rel >> 3) & 63, f = rel >> 9;
        int nf = f & 1, kk16 = f >> 1;
        int k = kk16 * 16 + (lane >> 5) * 8 + j;
        int ko = k >> 6, i = k & 63;
        int o = nf * 32 + (lane & 31);
        float v = (ko < 64) ? w2_1[ko * (64 * 64) + i * 64 + o]
                : (ko == 64 ? b2_1[i * 64 + o] : 0.f);
        BF1[rel] = (_Float16)v;
    }
}

// agg0[n,o] = bias0[o] + sum_i x[n,i]*root0[i,o]; also emits x in f16
__global__ void node_root_cvt(const float* __restrict__ x, const float* __restrict__ root,
                              const float* __restrict__ bias, float* __restrict__ agg,
                              _Float16* __restrict__ xb, int N) {
    int idx = blockIdx.x * 256 + threadIdx.x;
    if (idx >= N * 64) return;
    int n = idx >> 6, o = idx & 63;
    float s = bias[o];
    const float* xr = x + (size_t)n * 32;
    #pragma unroll 8
    for (int i = 0; i < 32; ++i) s += xr[i] * root[i * 64 + o];
    agg[idx] = s;
    if (o < 32) xb[n * 32 + o] = (_Float16)xr[o];
}

// x1b = f16(relu(agg0)); agg1[n,o] = bias1[o] + sum_i relu(agg0[n,i])*root1[i,o]
__global__ void mid_kernel(const float* __restrict__ agg0, const float* __restrict__ root1,
                           const float* __restrict__ bias1, _Float16* __restrict__ x1b,
                           float* __restrict__ agg1, int N) {
    int idx = blockIdx.x * 256 + threadIdx.x;
    if (idx >= N * 64) return;
    int n = idx >> 6, o = idx & 63;
    const float* ar = agg0 + (size_t)n * 64;
    float s = bias1[o];
    #pragma unroll 8
    for (int i = 0; i < 64; ++i) s += fmaxf(ar[i], 0.f) * root1[i * 64 + o];
    agg1[idx] = s;
    x1b[idx] = (_Float16)fmaxf(agg0[idx], 0.f);
}

__global__ void final_relu(const float* __restrict__ agg1, float* __restrict__ out, int n) {
    int idx = blockIdx.x * 256 + threadIdx.x;
    if (idx < n) out[idx] = fmaxf(agg1[idx], 0.f);
}

// ---------------------------------------------------------------------------
// Edge GEMM v9 = R6 dataflow + (a) 3-deep register pipeline, (b)
// amdgpu_waves_per_eu(3,3) to stop the allocator squeezing to 64 VGPR.
// 64-edge tile, 4 waves; wave = (nf, K-half), both mf (2 accumulators).
// No barrier / no LDS in the K-loop. K-halves combined via LDS, one barrier,
// one global atomic per element.
// ---------------------------------------------------------------------------
template<int IN_C>
__global__ __launch_bounds__(256) __attribute__((amdgpu_waves_per_eu(3, 3)))
void edge_gemm(const float* __restrict__ ea,
               const float* __restrict__ w1, const float* __restrict__ b1v,
               const _Float16* __restrict__ xb, const _Float16* __restrict__ BF,
               const int* __restrict__ srcI, const int* __restrict__ dstI,
               float* __restrict__ agg, int E) {
    constexpr int PH  = IN_C / 16;        // fragments per ko per nf
    constexpr int CPR = IN_C / 8;         // 16B chunks per x row

    __shared__ __align__(16) _Float16 sh_x[64][IN_C];
    __shared__ _Float16 sh_r1[64][70];
    __shared__ float buf[64][65];
    __shared__ int sh_dst[64];

    int tid = threadIdx.x;
    int ebase = blockIdx.x * 64;
    int valid = E - ebase; if (valid > 64) valid = 64;

    if (tid < 64) {
        sh_dst[tid] = (tid < valid) ? dstI[ebase + tid] : 0;
        sh_r1[tid][64] = (_Float16)1.f;
        #pragma unroll
        for (int c = 65; c < 70; ++c) sh_r1[tid][c] = (_Float16)0.f;
    }
    // r1 tile in-kernel: relu(ea @ w1 + b1)
    for (int i = tid; i < 64 * 64; i += 256) {
        int e = i >> 6, j = i & 63;
        int ge = (e < valid) ? (ebase + e) : ebase;
        float a0 = ea[ge * 2], a1 = ea[ge * 2 + 1];
        sh_r1[e][j] = (_Float16)fmaxf(a0 * w1[j] + a1 * w1[64 + j] + b1v[j], 0.f);
    }
    // gathered x tile (f16 source)
    for (int i = tid; i < 64 * CPR; i += 256) {
        int r = i / CPR, c = i - r * CPR;
        int sidx = (r < valid) ? srcI[ebase + r] : 0;
        *(uint4*)&sh_x[r][c * 8] = *(const uint4*)(xb + (size_t)sidx * IN_C + (size_t)c * 8);
    }
    __syncthreads();

    int wv = tid >> 6, lane = tid & 63, ln = lane & 31, g2 = lane >> 5;
    int nf = wv & 1, kh = wv >> 1;

    v8h xs0[PH], xs1[PH];
    #pragma unroll
    for (int p = 0; p < PH; ++p) {
        xs0[p] = *(const v8h*)&sh_x[ln][p * 16 + g2 * 8];
        xs1[p] = *(const v8h*)&sh_x[ln + 32][p * 16 + g2 * 8];
    }

    v16f acc0 = {0,0,0,0,0,0,0,0,0,0,0,0,0,0,0,0};
    v16f acc1 = acc0;

    // frag(ko,p) uint4 index: (ko*PH+p)*128 + nf*64 + lane
    const uint4* bp = (const uint4*)BF + (size_t)nf * 64 + lane;
    int kb = kh * 33;                      // K-half: ko in [kb, kb+33)

    uint4 pb0[PH], pb1[PH], pb2[PH];
    auto LD = [&](uint4 (&d)[PH], int ko) {
        #pragma unroll
        for (int p = 0; p < PH; ++p) d[p] = bp[(size_t)(ko * PH + p) * 128];
    };
    auto FM = [&](uint4 (&d)[PH], int ko) {
        _Float16 sv0 = sh_r1[ln][ko];
        _Float16 sv1 = sh_r1[ln + 32][ko];
        #pragma unroll
        for (int p = 0; p < PH; ++p) {
            v8h bb; __builtin_memcpy(&bb, &d[p], 16);
            v8h a0 = xs0[p] * sv0;
            v8h a1 = xs1[p] * sv1;
            acc0 = __builtin_amdgcn_mfma_f32_32x32x16_f16(a0, bb, acc0, 0, 0, 0);
            acc1 = __builtin_amdgcn_mfma_f32_32x32x16_f16(a1, bb, acc1, 0, 0, 0);
        }
    };

    LD(pb0, kb);
    LD(pb1, kb + 1);
    #pragma unroll 1
    for (int t = 0; t < 11; ++t) {         // 33 ko = 11 x 3, 2-ko lookahead
        int base = kb + 3 * t;
        LD(pb2, base + 2);
        FM(pb0, base);
        LD(pb0, base + 3);                 // overrun <=67: inside zero-pad
        FM(pb1, base + 1);
        LD(pb1, base + 4);
        FM(pb2, base + 2);
    }

    // combine K-halves: kh=1 stores to LDS, kh=0 adds + ONE global atomic/elem
    int colb = nf * 32 + ln;
    if (kh == 1) {
        #pragma unroll
        for (int r = 0; r < 16; ++r) {
            int row = 4 * g2 + (r & 3) + 8 * (r >> 2);
            buf[row][colb]      = acc0[r];
            buf[row + 32][colb] = acc1[r];
        }
    }
    __syncthreads();
    if (kh == 0) {
        #pragma unroll
        for (int r = 0; r < 16; ++r) {
            int row = 4 * g2 + (r & 3) + 8 * (r >> 2);
            if (row < valid)
                atomicAdd(&agg[(size_t)sh_dst[row] * 64 + colb], acc0[r] + buf[row][colb]);
            int row1 = row + 32;
            if (row1 < valid)
                atomicAdd(&agg[(size_t)sh_dst[row1] * 64 + colb], acc1[r] + buf[row1][colb]);
        }
    }
}

// ---------------------------------------------------------------------------
extern "C" void kernel_launch(void* const* d_in, const int* in_sizes, int n_in,
                              void* d_out, int out_size, void* d_ws, size_t ws_size,
                              hipStream_t stream) {
    const float* x      = (const float*)d_in[0];
    const int*   ei     = (const int*)d_in[1];
    const float* ea     = (const float*)d_in[2];
    const float* w1_0   = (const float*)d_in[3];
    const float* b1_0   = (const float*)d_in[4];
    const float* w2_0   = (const float*)d_in[5];
    const float* b2_0   = (const float*)d_in[6];
    const float* root_0 = (const float*)d_in[7];
    const float* bias_0 = (const float*)d_in[8];
    const float* w1_1   = (const float*)d_in[9];
    const float* b1_1   = (const float*)d_in[10];
    const float* w2_1   = (const float*)d_in[11];
    const float* b2_1   = (const float*)d_in[12];
    const float* root_1 = (const float*)d_in[13];
    const float* bias_1 = (const float*)d_in[14];
    float* out = (float*)d_out;

    int N = in_sizes[0] / 32;
    int E = in_sizes[1] / 2;
    const int* srcI = ei;
    const int* dstI = ei + E;

    char* ws = (char*)d_ws;
    size_t off = 0;
    auto carve = [&](size_t bytes) {
        void* p = ws + off;
        off += (bytes + 255) & ~(size_t)255;
        return p;
    };
    _Float16* BF0  = (_Float16*)carve((size_t)NBF0 * 2);
    _Float16* BF1  = (_Float16*)carve((size_t)NBF1 * 2);
    _Float16* XB0  = (_Float16*)carve((size_t)N * 32 * 2);
    _Float16* X1B  = (_Float16*)carve((size_t)N * 64 * 2);
    float*    AGG0 = (float*)carve((size_t)N * 64 * 4);
    float*    AGG1 = (float*)carve((size_t)N * 64 * 4);

    int tbf = NBF0 + NBF1;
    prep_bf_both<<<(tbf + 255) / 256, 256, 0, stream>>>(w2_0, b2_0, BF0, w2_1, b2_1, BF1);
    node_root_cvt<<<(N * 64 + 255) / 256, 256, 0, stream>>>(x, root_0, bias_0, AGG0, XB0, N);

    int gblocks = (E + 63) / 64;
    edge_gemm<32><<<gblocks, 256, 0, stream>>>(ea, w1_0, b1_0, XB0, BF0, srcI, dstI, AGG0, E);

    mid_kernel<<<(N * 64 + 255) / 256, 256, 0, stream>>>(AGG0, root_1, bias_1, X1B, AGG1, N);

    edge_gemm<64><<<gblocks, 256, 0, stream>>>(ea, w1_1, b1_1, X1B, BF1, srcI, dstI, AGG1, E);

    final_relu<<<(N * 64 + 255) / 256, 256, 0, stream>>>(AGG1, out, N * 64);
}